// Round 8
// baseline (90.784 us; speedup 1.0000x reference)
//
#include <hip/hip_runtime.h>
#include <hip/hip_fp16.h>

#define TLEN 512
#define KLEN 11
#define XPAD 256          // left zero pad: covers idx >= -255 (pad <= 255)
#define XTOT 1024         // 16 KiB LDS; valid-lane reads proven <= slot 1022
#define NEGINF2 0xFC00FC00u

__device__ __forceinline__ unsigned pkmax_u(unsigned a, unsigned b) {
    unsigned d;
    asm("v_pk_max_f16 %0, %1, %2" : "=v"(d) : "v"(a), "v"(b));
    return d;
}
__device__ __forceinline__ unsigned pkadd_u(unsigned a, unsigned b) {
    unsigned d;
    asm("v_pk_add_f16 %0, %1, %2" : "=v"(d) : "v"(a), "v"(b));
    return d;
}
// acc += w2(SGPR) * h(VGPR)  — VOP3P permits one SGPR source
__device__ __forceinline__ void pkfma_s(unsigned& acc, unsigned w2s, unsigned h) {
    asm("v_pk_fma_f16 %0, %1, %2, %0" : "+v"(acc) : "s"(w2s), "v"(h));
}

__device__ __forceinline__ unsigned wred_pkmax(unsigned x) {
    unsigned t;
    t = __builtin_amdgcn_update_dpp((int)NEGINF2, (int)x, 0x111, 0xF, 0xF, false);
    x = pkmax_u(x, t);
    t = __builtin_amdgcn_update_dpp((int)NEGINF2, (int)x, 0x112, 0xF, 0xF, false);
    x = pkmax_u(x, t);
    t = __builtin_amdgcn_update_dpp((int)NEGINF2, (int)x, 0x114, 0xF, 0xF, false);
    x = pkmax_u(x, t);
    t = __builtin_amdgcn_update_dpp((int)NEGINF2, (int)x, 0x118, 0xF, 0xF, false);
    x = pkmax_u(x, t);
    t = __builtin_amdgcn_update_dpp((int)NEGINF2, (int)x, 0x142, 0xA, 0xF, false);
    x = pkmax_u(x, t);
    t = __builtin_amdgcn_update_dpp((int)NEGINF2, (int)x, 0x143, 0xC, 0xF, false);
    x = pkmax_u(x, t);
    return (unsigned)__builtin_amdgcn_readlane((int)x, 63);
}
__device__ __forceinline__ unsigned wred_pkadd(unsigned x) {
    unsigned t;
    t = __builtin_amdgcn_update_dpp(0, (int)x, 0x111, 0xF, 0xF, false);
    x = pkadd_u(x, t);
    t = __builtin_amdgcn_update_dpp(0, (int)x, 0x112, 0xF, 0xF, false);
    x = pkadd_u(x, t);
    t = __builtin_amdgcn_update_dpp(0, (int)x, 0x114, 0xF, 0xF, false);
    x = pkadd_u(x, t);
    t = __builtin_amdgcn_update_dpp(0, (int)x, 0x118, 0xF, 0xF, false);
    x = pkadd_u(x, t);
    t = __builtin_amdgcn_update_dpp(0, (int)x, 0x142, 0xA, 0xF, false);
    x = pkadd_u(x, t);
    t = __builtin_amdgcn_update_dpp(0, (int)x, 0x143, 0xC, 0xF, false);
    x = pkadd_u(x, t);
    return (unsigned)__builtin_amdgcn_readlane((int)x, 63);
}

__device__ __forceinline__ __half2 as_h2(unsigned u) {
    __half2 h; __builtin_memcpy(&h, &u, 4); return h;
}
__device__ __forceinline__ unsigned as_u(__half2 h) {
    unsigned u; __builtin_memcpy(&u, &h, 4); return u;
}

// Single fused kernel: build fp16 8-batch-interleaved padded window in LDS,
// then taps-outer / chunks-inner conv with persistent packed accumulators.
__global__ __launch_bounds__(256, 8) void rf_fused(
    const float* __restrict__ x, const float* __restrict__ weight,
    const float* __restrict__ bias, const int* __restrict__ dilation,
    const int* __restrict__ padding, const int* __restrict__ out_len,
    float* __restrict__ out, int K)
{
    __shared__ uint4 xs[XTOT];
    const int t = threadIdx.x;

    // ---- fused staging: zero pads + 2 window slots per thread ----
    const uint4 z = make_uint4(0u, 0u, 0u, 0u);
    xs[t] = z;             // left pad  [0,256)
    xs[768 + t] = z;       // right pad [768,1024)
    const float* xg = x + (size_t)blockIdx.y * 8 * TLEN;
    #pragma unroll
    for (int half_ = 0; half_ < 2; ++half_) {
        const int pos = t + half_ * 256;       // coalesced: lane-consecutive
        float v[8];
        #pragma unroll
        for (int q = 0; q < 8; ++q) v[q] = xg[q * TLEN + pos];
        uint4 s;
        s.x = as_u(__floats2half2_rn(v[0], v[1]));
        s.y = as_u(__floats2half2_rn(v[2], v[3]));
        s.z = as_u(__floats2half2_rn(v[4], v[5]));
        s.w = as_u(__floats2half2_rn(v[6], v[7]));
        xs[XPAD + pos] = s;                    // stride-16B: conflict-free
    }
    __syncthreads();

    const int lane = t & 63;
    const int ks = __builtin_amdgcn_readfirstlane(blockIdx.x * 4 + (t >> 6));

    const int dil  = dilation[ks];             // scalar (s_load)
    const int pd   = padding[ks];
    const int olen = out_len[ks];
    unsigned w2s[KLEN];
    bool wnz[KLEN];
    #pragma unroll
    for (int j = 0; j < KLEN; ++j) {
        const float wv = weight[ks * KLEN + j];            // SGPR
        wnz[j] = (wv != 0.0f);
        w2s[j] = __builtin_amdgcn_readfirstlane((int)as_u(__float2half2_rn(wv)));
    }
    const unsigned bias2 = __builtin_amdgcn_readfirstlane(
        (int)as_u(__float2half2_rn(bias[ks])));
    const __half2 zero2 = __float2half2_rn(0.0f);

    const int vbase = XPAD + lane - pd;

    unsigned acc[8][4];
    #pragma unroll
    for (int c = 0; c < 8; ++c)
        #pragma unroll
        for (int q = 0; q < 4; ++q) acc[c][q] = bias2;     // bias folded in

    #pragma unroll
    for (int j = 0; j < KLEN; ++j) {
        if (wnz[j]) {                                      // uniform skip
            const uint4* xp = xs + (vbase + j * dil);      // one addr per tap
            #pragma unroll
            for (int c = 0; c < 8; ++c) {
                if (c * 64 < olen) {                       // uniform skip
                    const uint4 r = xp[c * 64];            // ds_read_b128 imm
                    pkfma_s(acc[c][0], w2s[j], r.x);
                    pkfma_s(acc[c][1], w2s[j], r.y);
                    pkfma_s(acc[c][2], w2s[j], r.z);
                    pkfma_s(acc[c][3], w2s[j], r.w);
                }
            }
        }
    }

    // ---- packed epilogue ----
    unsigned mxu[4], cfu[4];
    #pragma unroll
    for (int q = 0; q < 4; ++q) { mxu[q] = NEGINF2; cfu[q] = 0u; }

    #pragma unroll
    for (int c = 0; c < 8; ++c) {
        const int p0 = c * 64;
        if (p0 + 64 <= olen) {                             // fully-valid chunk
            #pragma unroll
            for (int q = 0; q < 4; ++q) {
                mxu[q] = pkmax_u(mxu[q], acc[c][q]);
                cfu[q] = pkadd_u(cfu[q], as_u(__hgt2(as_h2(acc[c][q]), zero2)));
            }
        } else if (p0 < olen) {                            // boundary chunk
            const bool vld = lane < (olen - p0);
            #pragma unroll
            for (int q = 0; q < 4; ++q) {
                mxu[q] = pkmax_u(mxu[q], vld ? acc[c][q] : NEGINF2);
                const unsigned g = vld ? as_u(__hgt2(as_h2(acc[c][q]), zero2)) : 0u;
                cfu[q] = pkadd_u(cfu[q], g);
            }
        }
    }

    #pragma unroll
    for (int q = 0; q < 4; ++q) {
        mxu[q] = wred_pkmax(mxu[q]);
        cfu[q] = wred_pkadd(cfu[q]);
    }

    if (lane == 0) {
        const float inv = 1.0f / (float)olen;
        const size_t row = (size_t)2 * K;
        float* o = out + (size_t)blockIdx.y * 8 * row + 2 * ks;
        #pragma unroll
        for (int q = 0; q < 4; ++q) {
            const __half2 m = as_h2(mxu[q]);
            const __half2 c = as_h2(cfu[q]);
            *(float2*)(o + (2 * q) * row)     = make_float2(__low2float(m),  __low2float(c) * inv);
            *(float2*)(o + (2 * q + 1) * row) = make_float2(__high2float(m), __high2float(c) * inv);
        }
    }
}

extern "C" void kernel_launch(void* const* d_in, const int* in_sizes, int n_in,
                              void* d_out, int out_size, void* d_ws, size_t ws_size,
                              hipStream_t stream) {
    const float* x    = (const float*)d_in[0];
    const float* w    = (const float*)d_in[1];
    const float* bias = (const float*)d_in[2];
    const int* dil    = (const int*)d_in[3];
    const int* pad    = (const int*)d_in[4];
    const int* olen   = (const int*)d_in[5];
    float* out        = (float*)d_out;

    const int K = in_sizes[2];          // 4096
    const int B = in_sizes[0] / TLEN;   // 32

    dim3 grid(K / 4, B / 8);            // 1024 x 4 blocks, 4 waves each
    rf_fused<<<grid, 256, 0, stream>>>(x, w, bias, dil, pad, olen, out, K);
    (void)n_in; (void)out_size; (void)d_ws; (void)ws_size;
}